// Round 1
// baseline (926.863 us; speedup 1.0000x reference)
//
#include <hip/hip_runtime.h>
#include <math.h>

#define BB 2
#define SS 2048
#define DD 768
#define HH 12
#define DH 64
#define NROWS (BB*SS)      // 4096
#define ATT_SCALE 0.125f   // 64^-0.5

// ---------------------------------------------------------------------------
// Kernel 1: QKV projections. C = X @ W + b, scattered to [B,H,S,Dh].
// grid = (NROWS/64, DD/64, 3), block = 256. blockIdx.z selects q/k/v.
// ---------------------------------------------------------------------------
__global__ __launch_bounds__(256) void qkv_proj_kernel(
    const float* __restrict__ X,
    const float* __restrict__ Wq, const float* __restrict__ bq,
    const float* __restrict__ Wk, const float* __restrict__ bk,
    const float* __restrict__ Wv, const float* __restrict__ bv,
    float* __restrict__ qbuf, float* __restrict__ kbuf, float* __restrict__ vbuf)
{
    const int which = blockIdx.z;
    const float* W    = which == 0 ? Wq : (which == 1 ? Wk : Wv);
    const float* bias = which == 0 ? bq : (which == 1 ? bk : bv);
    float* out        = which == 0 ? qbuf : (which == 1 ? kbuf : vbuf);

    __shared__ float As[16][64];   // As[k][m] (transposed)
    __shared__ float Bs[16][64];   // Bs[k][n]

    const int tid = threadIdx.x;
    const int m0 = blockIdx.x * 64;
    const int n0 = blockIdx.y * 64;
    const int ty = tid >> 4;       // 0..15
    const int tx = tid & 15;       // 0..15

    const int la_m = tid >> 2;           // 0..63
    const int la_k = (tid & 3) * 4;      // 0,4,8,12
    const int lb_k = tid >> 4;           // 0..15
    const int lb_n = (tid & 15) * 4;     // 0..60

    float acc[4][4] = {};

    for (int k0 = 0; k0 < DD; k0 += 16) {
        __syncthreads();
        float4 a = *(const float4*)&X[(m0 + la_m) * DD + k0 + la_k];
        As[la_k + 0][la_m] = a.x;
        As[la_k + 1][la_m] = a.y;
        As[la_k + 2][la_m] = a.z;
        As[la_k + 3][la_m] = a.w;
        *(float4*)&Bs[lb_k][lb_n] = *(const float4*)&W[(k0 + lb_k) * DD + n0 + lb_n];
        __syncthreads();
        #pragma unroll
        for (int kk = 0; kk < 16; ++kk) {
            float4 av = *(const float4*)&As[kk][ty * 4];
            float4 bv4 = *(const float4*)&Bs[kk][tx * 4];
            float am[4] = {av.x, av.y, av.z, av.w};
            float bn[4] = {bv4.x, bv4.y, bv4.z, bv4.w};
            #pragma unroll
            for (int i = 0; i < 4; ++i)
                #pragma unroll
                for (int j = 0; j < 4; ++j)
                    acc[i][j] += am[i] * bn[j];
        }
    }

    // scatter to [B,H,S,Dh]
    #pragma unroll
    for (int i = 0; i < 4; ++i) {
        const int m = m0 + ty * 4 + i;
        const int b = m >> 11;
        const int s = m & 2047;
        #pragma unroll
        for (int j = 0; j < 4; ++j) {
            const int n = n0 + tx * 4 + j;
            const int h = n >> 6;
            const int d = n & 63;
            out[(((size_t)(b * HH + h)) * SS + s) * DH + d] = acc[i][j] + bias[n];
        }
    }
}

// ---------------------------------------------------------------------------
// Kernel 2: flash attention over one head. grid = (S/64, H, B), block = 256.
// Each block: 64 query rows; 4 threads per row (c = tid&3 owns 16 dims).
// K/V tiles (64x64 f32) staged in LDS. Online softmax. Output overwrites the
// block's own Q rows (exclusive ownership -> safe).
// ---------------------------------------------------------------------------
__global__ __launch_bounds__(256) void attn_kernel(
    float* qbuf, const float* __restrict__ kbuf, const float* __restrict__ vbuf)
{
    const int tid = threadIdx.x;
    const int r = tid >> 2;     // 0..63 query row within tile
    const int c = tid & 3;      // 0..3 dim-group
    const int q0 = blockIdx.x * 64;
    const int h = blockIdx.y;
    const int b = blockIdx.z;
    const size_t headbase = ((size_t)(b * HH + h)) * SS * DH;

    __shared__ float Ks[64][64];
    __shared__ float Vs[64][64];

    // Q row fragment in registers
    float q[16];
    #pragma unroll
    for (int j4 = 0; j4 < 4; ++j4) {
        float4 t = *(const float4*)&qbuf[headbase + (size_t)(q0 + r) * DH + c * 16 + j4 * 4];
        q[j4 * 4 + 0] = t.x; q[j4 * 4 + 1] = t.y;
        q[j4 * 4 + 2] = t.z; q[j4 * 4 + 3] = t.w;
    }

    float o[16] = {};
    float mrun = -INFINITY;
    float lrun = 0.f;

    for (int kt = 0; kt < SS / 64; ++kt) {
        __syncthreads();
        const float* Kg = kbuf + headbase + (size_t)kt * 64 * DH;
        const float* Vg = vbuf + headbase + (size_t)kt * 64 * DH;
        #pragma unroll
        for (int i = 0; i < 4; ++i) {
            ((float4*)Ks)[i * 256 + tid] = ((const float4*)Kg)[i * 256 + tid];
            ((float4*)Vs)[i * 256 + tid] = ((const float4*)Vg)[i * 256 + tid];
        }
        __syncthreads();

        #pragma unroll
        for (int ch = 0; ch < 4; ++ch) {
            float sc[16];
            // partial dot over this thread's 16 dims
            #pragma unroll
            for (int kk = 0; kk < 16; ++kk) {
                const float* kr = &Ks[ch * 16 + kk][c * 16];
                float4 k0v = *(const float4*)(kr + 0);
                float4 k1v = *(const float4*)(kr + 4);
                float4 k2v = *(const float4*)(kr + 8);
                float4 k3v = *(const float4*)(kr + 12);
                float p;
                p  = q[0]  * k0v.x; p += q[1]  * k0v.y; p += q[2]  * k0v.z; p += q[3]  * k0v.w;
                p += q[4]  * k1v.x; p += q[5]  * k1v.y; p += q[6]  * k1v.z; p += q[7]  * k1v.w;
                p += q[8]  * k2v.x; p += q[9]  * k2v.y; p += q[10] * k2v.z; p += q[11] * k2v.w;
                p += q[12] * k3v.x; p += q[13] * k3v.y; p += q[14] * k3v.z; p += q[15] * k3v.w;
                sc[kk] = p;
            }
            // reduce across the 4 threads of this row; scale
            #pragma unroll
            for (int kk = 0; kk < 16; ++kk) {
                sc[kk] += __shfl_xor(sc[kk], 1);
                sc[kk] += __shfl_xor(sc[kk], 2);
                sc[kk] *= ATT_SCALE;
            }
            // online softmax update
            float cm = sc[0];
            #pragma unroll
            for (int kk = 1; kk < 16; ++kk) cm = fmaxf(cm, sc[kk]);
            const float mnew = fmaxf(mrun, cm);
            const float f = __expf(mrun - mnew);   // 0 on first chunk (mrun=-inf)
            lrun *= f;
            #pragma unroll
            for (int j = 0; j < 16; ++j) o[j] *= f;
            float ps = 0.f;
            #pragma unroll
            for (int kk = 0; kk < 16; ++kk) {
                sc[kk] = __expf(sc[kk] - mnew);
                ps += sc[kk];
            }
            lrun += ps;
            mrun = mnew;
            // PV accumulate
            #pragma unroll
            for (int kk = 0; kk < 16; ++kk) {
                const float* vr = &Vs[ch * 16 + kk][c * 16];
                float4 v0 = *(const float4*)(vr + 0);
                float4 v1 = *(const float4*)(vr + 4);
                float4 v2 = *(const float4*)(vr + 8);
                float4 v3 = *(const float4*)(vr + 12);
                const float p = sc[kk];
                o[0]  += p * v0.x; o[1]  += p * v0.y; o[2]  += p * v0.z; o[3]  += p * v0.w;
                o[4]  += p * v1.x; o[5]  += p * v1.y; o[6]  += p * v1.z; o[7]  += p * v1.w;
                o[8]  += p * v2.x; o[9]  += p * v2.y; o[10] += p * v2.z; o[11] += p * v2.w;
                o[12] += p * v3.x; o[13] += p * v3.y; o[14] += p * v3.z; o[15] += p * v3.w;
            }
        }
    }

    const float inv = 1.f / lrun;
    #pragma unroll
    for (int j4 = 0; j4 < 4; ++j4) {
        float4 t;
        t.x = o[j4 * 4 + 0] * inv; t.y = o[j4 * 4 + 1] * inv;
        t.z = o[j4 * 4 + 2] * inv; t.w = o[j4 * 4 + 3] * inv;
        *(float4*)&qbuf[headbase + (size_t)(q0 + r) * DH + c * 16 + j4 * 4] = t;
    }
}

// ---------------------------------------------------------------------------
// Kernel 3: output projection. A = attn out in [B,H,S,Dh] layout (gathered),
// C = A @ Wo + bo -> d_out [B,S,D]. grid = (NROWS/64, DD/64), block = 256.
// ---------------------------------------------------------------------------
__global__ __launch_bounds__(256) void out_proj_kernel(
    const float* __restrict__ abuf,
    const float* __restrict__ Wo, const float* __restrict__ bo,
    float* __restrict__ out)
{
    __shared__ float As[16][64];
    __shared__ float Bs[16][64];

    const int tid = threadIdx.x;
    const int m0 = blockIdx.x * 64;
    const int n0 = blockIdx.y * 64;
    const int ty = tid >> 4;
    const int tx = tid & 15;

    const int la_m = tid >> 2;
    const int la_k = (tid & 3) * 4;
    const int lb_k = tid >> 4;
    const int lb_n = (tid & 15) * 4;

    const int am = m0 + la_m;
    const int ab = am >> 11;
    const int as = am & 2047;

    float acc[4][4] = {};

    for (int k0 = 0; k0 < DD; k0 += 16) {
        __syncthreads();
        const int k = k0 + la_k;
        const int hh = k >> 6;
        const int dd = k & 63;
        float4 a = *(const float4*)&abuf[(((size_t)(ab * HH + hh)) * SS + as) * DH + dd];
        As[la_k + 0][la_m] = a.x;
        As[la_k + 1][la_m] = a.y;
        As[la_k + 2][la_m] = a.z;
        As[la_k + 3][la_m] = a.w;
        *(float4*)&Bs[lb_k][lb_n] = *(const float4*)&Wo[(k0 + lb_k) * DD + n0 + lb_n];
        __syncthreads();
        #pragma unroll
        for (int kk = 0; kk < 16; ++kk) {
            float4 av = *(const float4*)&As[kk][ty * 4];
            float4 bv4 = *(const float4*)&Bs[kk][tx * 4];
            float amv[4] = {av.x, av.y, av.z, av.w};
            float bnv[4] = {bv4.x, bv4.y, bv4.z, bv4.w};
            #pragma unroll
            for (int i = 0; i < 4; ++i)
                #pragma unroll
                for (int j = 0; j < 4; ++j)
                    acc[i][j] += amv[i] * bnv[j];
        }
    }

    #pragma unroll
    for (int i = 0; i < 4; ++i) {
        const int m = m0 + ty * 4 + i;
        #pragma unroll
        for (int j = 0; j < 4; ++j) {
            const int n = n0 + tx * 4 + j;
            out[(size_t)m * DD + n] = acc[i][j] + bo[n];
        }
    }
}

// ---------------------------------------------------------------------------
extern "C" void kernel_launch(void* const* d_in, const int* in_sizes, int n_in,
                              void* d_out, int out_size, void* d_ws, size_t ws_size,
                              hipStream_t stream)
{
    const float* x  = (const float*)d_in[0];
    const float* Wq = (const float*)d_in[1];
    const float* bq = (const float*)d_in[2];
    const float* Wk = (const float*)d_in[3];
    const float* bk = (const float*)d_in[4];
    const float* Wv = (const float*)d_in[5];
    const float* bv = (const float*)d_in[6];
    const float* Wo = (const float*)d_in[7];
    const float* bo = (const float*)d_in[8];

    float* ws = (float*)d_ws;
    const size_t elems = (size_t)BB * HH * SS * DH;  // 3,145,728 per buffer
    float* qbuf = ws;               // becomes attn output in place
    float* kbuf = ws + elems;
    float* vbuf = ws + 2 * elems;

    dim3 g1(NROWS / 64, DD / 64, 3);
    qkv_proj_kernel<<<g1, 256, 0, stream>>>(x, Wq, bq, Wk, bk, Wv, bv, qbuf, kbuf, vbuf);

    dim3 g2(SS / 64, HH, BB);
    attn_kernel<<<g2, 256, 0, stream>>>(qbuf, kbuf, vbuf);

    dim3 g3(NROWS / 64, DD / 64);
    out_proj_kernel<<<g3, 256, 0, stream>>>(qbuf, Wo, bo, (float*)d_out);
}

// Round 2
// 160.372 us; speedup vs baseline: 5.7795x; 5.7795x over previous
//
#include <hip/hip_runtime.h>
#include <math.h>

#define BB 2
#define SS 2048
#define DDIM 768
#define HH 12
#define DH 64
#define NROWS (BB*SS)            // 4096
#define NTOK_D (NROWS*DDIM)      // 3145728

typedef _Float16 f16;
typedef _Float16 half8 __attribute__((ext_vector_type(8)));
typedef float f32x4 __attribute__((ext_vector_type(4)));

#define MFMA16(a,b,c) __builtin_amdgcn_mfma_f32_16x16x32_f16((a),(b),(c),0,0,0)

// swizzled byte offset inside a 128B LDS row: 16B slot index ^= (row&7)
__device__ __forceinline__ int swz(int row, int chunk16) {
    return row*128 + ((chunk16 ^ (row & 7)) << 4);
}

// ---------------------------------------------------------------------------
// prep: x (f32) -> Xh (f16). 1536 blocks x 256 thr, 8 elems/thread, exact.
// ---------------------------------------------------------------------------
__global__ __launch_bounds__(256) void prep_x(const float* __restrict__ x, f16* __restrict__ xh)
{
    int i = blockIdx.x * 256 + threadIdx.x;
    const float4* in = (const float4*)x;
    float4 a = in[i*2], b = in[i*2+1];
    half8 h = {(f16)a.x,(f16)a.y,(f16)a.z,(f16)a.w,(f16)b.x,(f16)b.y,(f16)b.z,(f16)b.w};
    *(half8*)(xh + (size_t)i*8) = h;
}

// ---------------------------------------------------------------------------
// prep: W[k][n] (f32) -> Wt[n][k] (f16), 4 matrices. grid (12,12,4), 256 thr.
// ---------------------------------------------------------------------------
__global__ __launch_bounds__(256) void prep_w(const float* __restrict__ Wq, const float* __restrict__ Wk,
                                              const float* __restrict__ Wv, const float* __restrict__ Wo,
                                              f16* __restrict__ Wt)
{
    const int z = blockIdx.z;
    const float* W = z==0 ? Wq : (z==1 ? Wk : (z==2 ? Wv : Wo));
    f16* out = Wt + (size_t)z * DDIM * DDIM;

    __shared__ float tile[64][65];
    const int t = threadIdx.x;
    const int k0 = blockIdx.x*64, n0 = blockIdx.y*64;

    const int kr = t >> 2, nc = (t & 3) * 16;
    #pragma unroll
    for (int i = 0; i < 4; ++i) {
        float4 v = *(const float4*)&W[(size_t)(k0+kr)*DDIM + n0 + nc + i*4];
        tile[kr][nc+i*4+0] = v.x; tile[kr][nc+i*4+1] = v.y;
        tile[kr][nc+i*4+2] = v.z; tile[kr][nc+i*4+3] = v.w;
    }
    __syncthreads();
    const int nr = t >> 2, kc = (t & 3) * 16;
    half8 h0, h1;
    #pragma unroll
    for (int j = 0; j < 8; ++j) {
        h0[j] = (f16)tile[kc + j][nr];
        h1[j] = (f16)tile[kc + 8 + j][nr];
    }
    *(half8*)&out[(size_t)(n0+nr)*DDIM + k0 + kc]     = h0;
    *(half8*)&out[(size_t)(n0+nr)*DDIM + k0 + kc + 8] = h1;
}

// ---------------------------------------------------------------------------
// QKV projection: C = Xh @ Wz + bias -> [B,H,S,Dh] f16 (q pre-scaled 0.125).
// grid (4096/64, 768/128, 3), 256 thr (4 waves, 2x2), BK=64, 16x16x32 MFMA.
// ---------------------------------------------------------------------------
__global__ __launch_bounds__(256) void proj_qkv(const f16* __restrict__ Xh, const f16* __restrict__ Wt,
        const float* __restrict__ bq, const float* __restrict__ bk, const float* __restrict__ bv,
        f16* __restrict__ qb, f16* __restrict__ kb2, f16* __restrict__ vb2)
{
    const int z = blockIdx.z;
    const f16* Wz = Wt + (size_t)z * DDIM * DDIM;
    const float* bias = z==0 ? bq : (z==1 ? bk : bv);
    f16* out = z==0 ? qb : (z==1 ? kb2 : vb2);
    const float qscale = (z==0) ? 0.125f : 1.0f;

    __shared__ __align__(16) unsigned char lds[24*1024];
    unsigned char* As = lds;            // 64 rows x 128B (m x k f16)
    unsigned char* Bs = lds + 8*1024;   // 128 rows x 128B (n x k f16)

    const int tid = threadIdx.x;
    const int l = tid & 63, w = tid >> 6;
    const int wm = w >> 1, wn = w & 1;
    const int m0 = blockIdx.x * 64, n0 = blockIdx.y * 128;

    f32x4 acc[2][4];
    #pragma unroll
    for (int i=0;i<2;i++)
        #pragma unroll
        for (int j=0;j<4;j++) { f32x4 zv = {0.f,0.f,0.f,0.f}; acc[i][j] = zv; }

    for (int k0 = 0; k0 < DDIM; k0 += 64) {
        __syncthreads();
        #pragma unroll
        for (int i = 0; i < 2; ++i) {           // A: 512 chunks
            int c = tid + i*256;
            int row = c >> 3, kc = c & 7;
            half8 v = *(const half8*)&Xh[(size_t)(m0+row)*DDIM + k0 + kc*8];
            *(half8*)(As + swz(row, kc)) = v;
        }
        #pragma unroll
        for (int i = 0; i < 4; ++i) {           // B: 1024 chunks
            int c = tid + i*256;
            int row = c >> 3, kc = c & 7;
            half8 v = *(const half8*)&Wz[(size_t)(n0+row)*DDIM + k0 + kc*8];
            *(half8*)(Bs + swz(row, kc)) = v;
        }
        __syncthreads();

        half8 af[2][2], bf[4][2];
        #pragma unroll
        for (int mt = 0; mt < 2; ++mt) {
            int row = wm*32 + mt*16 + (l & 15);
            #pragma unroll
            for (int kh = 0; kh < 2; ++kh)
                af[mt][kh] = *(const half8*)(As + swz(row, kh*4 + (l>>4)));
        }
        #pragma unroll
        for (int nt = 0; nt < 4; ++nt) {
            int row = wn*64 + nt*16 + (l & 15);
            #pragma unroll
            for (int kh = 0; kh < 2; ++kh)
                bf[nt][kh] = *(const half8*)(Bs + swz(row, kh*4 + (l>>4)));
        }
        #pragma unroll
        for (int mt = 0; mt < 2; ++mt)
            #pragma unroll
            for (int nt = 0; nt < 4; ++nt) {
                acc[mt][nt] = MFMA16(af[mt][0], bf[nt][0], acc[mt][nt]);
                acc[mt][nt] = MFMA16(af[mt][1], bf[nt][1], acc[mt][nt]);
            }
    }

    #pragma unroll
    for (int mt = 0; mt < 2; ++mt)
        #pragma unroll
        for (int nt = 0; nt < 4; ++nt)
            #pragma unroll
            for (int r = 0; r < 4; ++r) {
                int m = m0 + wm*32 + mt*16 + (l>>4)*4 + r;
                int n = n0 + wn*64 + nt*16 + (l & 15);
                float v = (acc[mt][nt][r] + bias[n]) * qscale;
                int b = m >> 11, s = m & 2047;
                int h = n >> 6,  d = n & 63;
                out[(((size_t)(b*HH + h))*SS + s)*DH + d] = (f16)v;
            }
}

// ---------------------------------------------------------------------------
// Flash attention, fp16 MFMA. grid (32, 12, 2), 256 thr = 4 waves x 16 q-rows.
// K row-major + V transposed in LDS (XOR swizzle); P via per-wave LDS buffer.
// ---------------------------------------------------------------------------
__global__ __launch_bounds__(256) void attn_mfma(const f16* __restrict__ qbuf, const f16* __restrict__ kbuf,
                                                 const f16* __restrict__ vbuf, f16* __restrict__ obuf)
{
    __shared__ __align__(16) unsigned char lds[24*1024];
    unsigned char* Ks = lds;            // [key 0..63] x 128B (d f16)
    unsigned char* Vt = lds + 8192;     // [d 0..63]   x 128B (key f16)
    unsigned char* Ps = lds + 16384;    // 4 waves x (16 q-rows x 128B)

    const int tid = threadIdx.x;
    const int l = tid & 63, w = tid >> 6;
    const int q0 = blockIdx.x * 64;
    const size_t base = ((size_t)(blockIdx.z * HH + blockIdx.y)) * SS * DH;
    unsigned char* Pw = Ps + w * 2048;

    // Q fragments (q pre-scaled by 0.125 in proj)
    half8 qa[2];
    {
        int q = q0 + w*16 + (l & 15);
        #pragma unroll
        for (int kh = 0; kh < 2; ++kh)
            qa[kh] = *(const half8*)&qbuf[base + (size_t)q*DH + (kh*4 + (l>>4))*8];
    }

    f32x4 oacc[4];
    #pragma unroll
    for (int i=0;i<4;i++) { f32x4 zv = {0.f,0.f,0.f,0.f}; oacc[i] = zv; }
    float mrun[4] = {-INFINITY,-INFINITY,-INFINITY,-INFINITY};
    float lsum[4] = {0.f,0.f,0.f,0.f};

    const int skey = tid >> 2, sc4 = tid & 3;

    for (int kt = 0; kt < SS/64; ++kt) {
        const int key0 = kt * 64;
        __syncthreads();
        // stage K (row-major, swizzled)
        #pragma unroll
        for (int i = 0; i < 2; ++i) {
            int kc = sc4 + i*4;
            half8 v = *(const half8*)&kbuf[base + (size_t)(key0+skey)*DH + kc*8];
            *(half8*)(Ks + swz(skey, kc)) = v;
        }
        // stage V transposed (u16 scatter, swizzled)
        #pragma unroll
        for (int i = 0; i < 2; ++i) {
            int dc = sc4 + i*4;
            half8 v = *(const half8*)&vbuf[base + (size_t)(key0+skey)*DH + dc*8];
            #pragma unroll
            for (int j = 0; j < 8; ++j) {
                int d = dc*8 + j;
                *(f16*)(Vt + swz(d, skey>>3) + (skey & 7)*2) = v[j];
            }
        }
        __syncthreads();

        // QK^T: S[16q][64key], scaled already
        f32x4 sv[4];
        #pragma unroll
        for (int nt = 0; nt < 4; ++nt) {
            int key = nt*16 + (l & 15);
            half8 b0 = *(const half8*)(Ks + swz(key, (l>>4)));
            half8 b1 = *(const half8*)(Ks + swz(key, 4 + (l>>4)));
            f32x4 a0 = {0.f,0.f,0.f,0.f};
            a0 = MFMA16(qa[0], b0, a0);
            a0 = MFMA16(qa[1], b1, a0);
            sv[nt] = a0;
        }

        // online softmax (rows q = (l>>4)*4 + r; 16 lanes per row share l>>4)
        float p[4][4];
        #pragma unroll
        for (int r = 0; r < 4; ++r) {
            float tm = fmaxf(fmaxf(sv[0][r], sv[1][r]), fmaxf(sv[2][r], sv[3][r]));
            tm = fmaxf(tm, __shfl_xor(tm, 1));
            tm = fmaxf(tm, __shfl_xor(tm, 2));
            tm = fmaxf(tm, __shfl_xor(tm, 4));
            tm = fmaxf(tm, __shfl_xor(tm, 8));
            float mn = fmaxf(mrun[r], tm);
            float f = __expf(mrun[r] - mn);
            mrun[r] = mn;
            float rs = 0.f;
            #pragma unroll
            for (int nt = 0; nt < 4; ++nt) { float pp = __expf(sv[nt][r] - mn); p[nt][r] = pp; rs += pp; }
            rs += __shfl_xor(rs, 1); rs += __shfl_xor(rs, 2);
            rs += __shfl_xor(rs, 4); rs += __shfl_xor(rs, 8);
            lsum[r] = lsum[r]*f + rs;
            #pragma unroll
            for (int nt2 = 0; nt2 < 4; ++nt2) oacc[nt2][r] *= f;
        }

        // P -> LDS (fp16, A-frag re-layout), per-wave buffer
        #pragma unroll
        for (int nt = 0; nt < 4; ++nt)
            #pragma unroll
            for (int r = 0; r < 4; ++r) {
                int ql = (l>>4)*4 + r;
                int key = nt*16 + (l & 15);
                *(f16*)(Pw + swz(ql, key>>3) + (key & 7)*2) = (f16)p[nt][r];
            }

        // PV: O[16q][64d] += P[16][64] @ V[64][64]
        half8 pa0, pa1;
        {
            int ql = l & 15;
            pa0 = *(const half8*)(Pw + swz(ql, (l>>4)));
            pa1 = *(const half8*)(Pw + swz(ql, 4 + (l>>4)));
        }
        #pragma unroll
        for (int nt2 = 0; nt2 < 4; ++nt2) {
            int d = nt2*16 + (l & 15);
            half8 v0 = *(const half8*)(Vt + swz(d, (l>>4)));
            half8 v1 = *(const half8*)(Vt + swz(d, 4 + (l>>4)));
            oacc[nt2] = MFMA16(pa0, v0, oacc[nt2]);
            oacc[nt2] = MFMA16(pa1, v1, oacc[nt2]);
        }
    }

    #pragma unroll
    for (int nt2 = 0; nt2 < 4; ++nt2)
        #pragma unroll
        for (int r = 0; r < 4; ++r) {
            int q = q0 + w*16 + (l>>4)*4 + r;
            int d = nt2*16 + (l & 15);
            obuf[base + (size_t)q*DH + d] = (f16)(oacc[nt2][r] / lsum[r]);
        }
}

// ---------------------------------------------------------------------------
// Output projection: C = obuf(gathered) @ Wo^T' + bo -> f32 out [4096][768].
// grid (64, 6), 256 thr, same GEMM structure.
// ---------------------------------------------------------------------------
__global__ __launch_bounds__(256) void proj_out(const f16* __restrict__ obuf, const f16* __restrict__ Wt,
                                                const float* __restrict__ bo, float* __restrict__ out)
{
    const f16* Wz = Wt + (size_t)3 * DDIM * DDIM;

    __shared__ __align__(16) unsigned char lds[24*1024];
    unsigned char* As = lds;
    unsigned char* Bs = lds + 8*1024;

    const int tid = threadIdx.x;
    const int l = tid & 63, w = tid >> 6;
    const int wm = w >> 1, wn = w & 1;
    const int m0 = blockIdx.x * 64, n0 = blockIdx.y * 128;

    f32x4 acc[2][4];
    #pragma unroll
    for (int i=0;i<2;i++)
        #pragma unroll
        for (int j=0;j<4;j++) { f32x4 zv = {0.f,0.f,0.f,0.f}; acc[i][j] = zv; }

    for (int k0 = 0; k0 < DDIM; k0 += 64) {
        const int h = k0 >> 6;
        __syncthreads();
        #pragma unroll
        for (int i = 0; i < 2; ++i) {
            int c = tid + i*256;
            int row = c >> 3, kc = c & 7;
            int m = m0 + row, b = m >> 11, s = m & 2047;
            half8 v = *(const half8*)&obuf[(((size_t)(b*HH + h))*SS + s)*DH + kc*8];
            *(half8*)(As + swz(row, kc)) = v;
        }
        #pragma unroll
        for (int i = 0; i < 4; ++i) {
            int c = tid + i*256;
            int row = c >> 3, kc = c & 7;
            half8 v = *(const half8*)&Wz[(size_t)(n0+row)*DDIM + k0 + kc*8];
            *(half8*)(Bs + swz(row, kc)) = v;
        }
        __syncthreads();

        half8 af[2][2], bf[4][2];
        #pragma unroll
        for (int mt = 0; mt < 2; ++mt) {
            int row = wm*32 + mt*16 + (l & 15);
            #pragma unroll
            for (int kh = 0; kh < 2; ++kh)
                af[mt][kh] = *(const half8*)(As + swz(row, kh*4 + (l>>4)));
        }
        #pragma unroll
        for (int nt = 0; nt < 4; ++nt) {
            int row = wn*64 + nt*16 + (l & 15);
            #pragma unroll
            for (int kh = 0; kh < 2; ++kh)
                bf[nt][kh] = *(const half8*)(Bs + swz(row, kh*4 + (l>>4)));
        }
        #pragma unroll
        for (int mt = 0; mt < 2; ++mt)
            #pragma unroll
            for (int nt = 0; nt < 4; ++nt) {
                acc[mt][nt] = MFMA16(af[mt][0], bf[nt][0], acc[mt][nt]);
                acc[mt][nt] = MFMA16(af[mt][1], bf[nt][1], acc[mt][nt]);
            }
    }

    #pragma unroll
    for (int mt = 0; mt < 2; ++mt)
        #pragma unroll
        for (int nt = 0; nt < 4; ++nt)
            #pragma unroll
            for (int r = 0; r < 4; ++r) {
                int m = m0 + wm*32 + mt*16 + (l>>4)*4 + r;
                int n = n0 + wn*64 + nt*16 + (l & 15);
                out[(size_t)m*DDIM + n] = acc[mt][nt][r] + bo[n];
            }
}

// ---------------------------------------------------------------------------
extern "C" void kernel_launch(void* const* d_in, const int* in_sizes, int n_in,
                              void* d_out, int out_size, void* d_ws, size_t ws_size,
                              hipStream_t stream)
{
    const float* x  = (const float*)d_in[0];
    const float* Wq = (const float*)d_in[1];
    const float* bq = (const float*)d_in[2];
    const float* Wk = (const float*)d_in[3];
    const float* bk = (const float*)d_in[4];
    const float* Wv = (const float*)d_in[5];
    const float* bv = (const float*)d_in[6];
    const float* Wo = (const float*)d_in[7];
    const float* bo = (const float*)d_in[8];

    char* ws = (char*)d_ws;
    const size_t XH_B  = (size_t)NTOK_D * 2;            // 6,291,456
    const size_t WT_B  = (size_t)4 * DDIM * DDIM * 2;   // 4,718,592
    const size_t HB_B  = (size_t)BB * HH * SS * DH * 2; // 6,291,456

    f16* Xh = (f16*)ws;
    f16* Wt = (f16*)(ws + XH_B);
    f16* qb = (f16*)(ws + XH_B + WT_B);
    f16* kb = (f16*)(ws + XH_B + WT_B + HB_B);
    f16* vb = (f16*)(ws + XH_B + WT_B + 2*HB_B);
    f16* ob = (f16*)(ws + XH_B + WT_B + 3*HB_B);        // end ~36.2 MB

    prep_x<<<NTOK_D/(256*8), 256, 0, stream>>>(x, Xh);
    prep_w<<<dim3(DDIM/64, DDIM/64, 4), 256, 0, stream>>>(Wq, Wk, Wv, Wo, Wt);
    proj_qkv<<<dim3(NROWS/64, DDIM/128, 3), 256, 0, stream>>>(Xh, Wt, bq, bk, bv, qb, kb, vb);
    attn_mfma<<<dim3(SS/64, HH, BB), 256, 0, stream>>>(qb, kb, vb, ob);
    proj_out<<<dim3(NROWS/64, DDIM/128), 256, 0, stream>>>(ob, Wt, bo, (float*)d_out);
}